// Round 1
// baseline (1140.873 us; speedup 1.0000x reference)
//
#include <hip/hip_runtime.h>
#include <hip/hip_bf16.h>
#include <stdint.h>

#define N_H   128
#define N_INV 96
#define N_IN  320
#define BM    64
#define XS    328   // X tile stride in bf16 elems (320 + 8 pad -> 2-way bank alias, free)
#define HS    136   // H tile stride (128 + 8 pad)

typedef __bf16 bf16x8 __attribute__((ext_vector_type(8)));
typedef float  f32x4  __attribute__((ext_vector_type(4)));

__device__ __forceinline__ unsigned short f2bf(float f) {
    union { float f; unsigned u; } v; v.f = f;
    unsigned u = v.u;
    u += 0x7FFFu + ((u >> 16) & 1u);   // round-to-nearest-even
    return (unsigned short)(u >> 16);
}

// Convert W1 [320][128] -> W1^T bf16 [128][320]; W2 [128][128] -> W2^T bf16 [128][128]
__global__ void prep_weights(const float* __restrict__ W1,
                             const float* __restrict__ W2,
                             unsigned short* __restrict__ w1t,
                             unsigned short* __restrict__ w2t) {
    int idx = blockIdx.x * blockDim.x + threadIdx.x;
    if (idx < N_H * N_IN) {
        int n = idx / N_IN, k = idx % N_IN;
        w1t[idx] = f2bf(W1[(size_t)k * N_H + n]);
    } else if (idx < N_H * N_IN + N_H * N_H) {
        int j = idx - N_H * N_IN;
        int n = j / N_H, k = j % N_H;
        w2t[j] = f2bf(W2[(size_t)k * N_H + n]);
    }
}

__global__ __launch_bounds__(256, 2)
void edge_mlp(const float* __restrict__ ninv, const float* __restrict__ ef,
              const int* __restrict__ ei,
              const unsigned short* __restrict__ w1t,
              const unsigned short* __restrict__ w2t,
              const float* __restrict__ b1, const float* __restrict__ b2,
              const float* __restrict__ gamma, const float* __restrict__ beta,
              float* __restrict__ out, int E) {
    __shared__ __align__(16) unsigned short xlds[BM * XS];   // 41984 B
    __shared__ __align__(16) unsigned short hlds[BM * HS];   // 17408 B
    __shared__ int sidx[BM];
    __shared__ int didx[BM];

    const int tid = threadIdx.x;
    const int e0  = (int)blockIdx.x * BM;

    // stage edge indices once
    if (tid < BM) {
        int e = e0 + tid; if (e >= E) e = E - 1;
        sidx[tid] = ei[e];
        didx[tid] = ei[(size_t)E + e];
    }
    __syncthreads();

    // ---- stage X = [src(96) | dst(96) | ef(128)] as bf16 into LDS ----
    // 64 rows x 80 float4-chunks; consecutive tids -> consecutive 16B chunks (coalesced)
    #pragma unroll
    for (int it = 0; it < (BM * (N_IN / 4)) / 256; ++it) {
        int idx   = it * 256 + tid;
        int row   = idx / (N_IN / 4);
        int chunk = idx % (N_IN / 4);
        int e = e0 + row; if (e >= E) e = E - 1;
        const float* srcp;
        if (chunk < 24)      srcp = ninv + (size_t)sidx[row] * N_INV + chunk * 4;
        else if (chunk < 48) srcp = ninv + (size_t)didx[row] * N_INV + (chunk - 24) * 4;
        else                 srcp = ef + (size_t)e * N_H + (chunk - 48) * 4;
        float4 v = *(const float4*)srcp;
        ushort4 p = make_ushort4(f2bf(v.x), f2bf(v.y), f2bf(v.z), f2bf(v.w));
        *(ushort4*)(&xlds[row * XS + chunk * 4]) = p;
    }
    __syncthreads();

    const int lane = tid & 63;
    const int wv   = tid >> 6;          // wave 0..3, owns rows 16*wv .. 16*wv+15
    const int lr   = lane & 15;         // A row / B col / D col
    const int lk   = (lane >> 4) * 8;   // k offset within 32-step

    // ---- GEMM1: [16 x 320] x [320 x 128] ----
    f32x4 acc[8] = {};
    const unsigned short* xrow = &xlds[(wv * 16 + lr) * XS];
    #pragma unroll
    for (int ks = 0; ks < N_IN / 32; ++ks) {
        bf16x8 a = *(const bf16x8*)(xrow + ks * 32 + lk);
        #pragma unroll
        for (int nt = 0; nt < 8; ++nt) {
            bf16x8 b = *(const bf16x8*)(w1t + (size_t)(nt * 16 + lr) * N_IN + ks * 32 + lk);
            acc[nt] = __builtin_amdgcn_mfma_f32_16x16x32_bf16(a, b, acc[nt], 0, 0, 0);
        }
    }

    // ---- bias + ReLU -> bf16 H tile (wave-local rows; no barrier needed) ----
    // C/D layout: col = lane&15, row = (lane>>4)*4 + i   [m89]
    const int qr = (lane >> 4) * 4;
    #pragma unroll
    for (int nt = 0; nt < 8; ++nt) {
        float bb = b1[nt * 16 + lr];
        #pragma unroll
        for (int i = 0; i < 4; ++i) {
            float v = acc[nt][i] + bb;
            v = v > 0.0f ? v : 0.0f;
            hlds[(wv * 16 + qr + i) * HS + nt * 16 + lr] = f2bf(v);
        }
    }

    // ---- GEMM2: [16 x 128] x [128 x 128] ----
    f32x4 acc2[8] = {};
    const unsigned short* hrow = &hlds[(wv * 16 + lr) * HS];
    #pragma unroll
    for (int ks = 0; ks < N_H / 32; ++ks) {
        bf16x8 a = *(const bf16x8*)(hrow + ks * 32 + lk);
        #pragma unroll
        for (int nt = 0; nt < 8; ++nt) {
            bf16x8 b = *(const bf16x8*)(w2t + (size_t)(nt * 16 + lr) * N_H + ks * 32 + lk);
            acc2[nt] = __builtin_amdgcn_mfma_f32_16x16x32_bf16(a, b, acc2[nt], 0, 0, 0);
        }
    }

    // ---- bias + LayerNorm (per row of 128) + residual + store ----
    // Row r = 16*wv + qr + i lives in the 16 lanes sharing (lane>>4); each lane holds 8 cols.
    float vals[8][4];
    float s1[4] = {0.f, 0.f, 0.f, 0.f};
    float s2[4] = {0.f, 0.f, 0.f, 0.f};
    #pragma unroll
    for (int nt = 0; nt < 8; ++nt) {
        float bb = b2[nt * 16 + lr];
        #pragma unroll
        for (int i = 0; i < 4; ++i) {
            float v = acc2[nt][i] + bb;
            vals[nt][i] = v;
            s1[i] += v;
            s2[i] += v * v;
        }
    }
    #pragma unroll
    for (int m = 1; m < 16; m <<= 1) {
        #pragma unroll
        for (int i = 0; i < 4; ++i) {
            s1[i] += __shfl_xor(s1[i], m);
            s2[i] += __shfl_xor(s2[i], m);
        }
    }
    float mu[4], rs[4];
    #pragma unroll
    for (int i = 0; i < 4; ++i) {
        mu[i] = s1[i] * (1.0f / 128.0f);
        float var = s2[i] * (1.0f / 128.0f) - mu[i] * mu[i];
        rs[i] = rsqrtf(var + 1e-5f);
    }

    const int rbase = e0 + wv * 16 + qr;
    #pragma unroll
    for (int nt = 0; nt < 8; ++nt) {
        int c = nt * 16 + lr;
        float g  = gamma[c];
        float bt = beta[c];
        #pragma unroll
        for (int i = 0; i < 4; ++i) {
            int e = rbase + i;
            if (e < E) {
                float r = ef[(size_t)e * N_H + c];
                out[(size_t)e * N_H + c] = (vals[nt][i] - mu[i]) * rs[i] * g + bt + r;
            }
        }
    }
}

extern "C" void kernel_launch(void* const* d_in, const int* in_sizes, int n_in,
                              void* d_out, int out_size, void* d_ws, size_t ws_size,
                              hipStream_t stream) {
    const float* ninv = (const float*)d_in[0];
    const float* ef   = (const float*)d_in[1];
    const int*   ei   = (const int*)d_in[2];
    const float* W1   = (const float*)d_in[3];
    const float* b1   = (const float*)d_in[4];
    const float* W2   = (const float*)d_in[5];
    const float* b2   = (const float*)d_in[6];
    const float* g    = (const float*)d_in[7];
    const float* bt   = (const float*)d_in[8];
    float* out = (float*)d_out;

    const int E = in_sizes[1] / N_H;

    unsigned short* w1t = (unsigned short*)d_ws;             // 128*320 bf16
    unsigned short* w2t = w1t + N_H * N_IN;                  // 128*128 bf16

    int prep_total = N_H * N_IN + N_H * N_H;
    prep_weights<<<(prep_total + 255) / 256, 256, 0, stream>>>(W1, W2, w1t, w2t);

    int nblk = (E + BM - 1) / BM;
    edge_mlp<<<nblk, 256, 0, stream>>>(ninv, ef, ei, w1t, w2t, b1, b2, g, bt, out, E);
}

// Round 2
// 817.092 us; speedup vs baseline: 1.3963x; 1.3963x over previous
//
#include <hip/hip_runtime.h>
#include <stdint.h>

#define N_H   128
#define N_INV 96
#define N_IN  320
#define HS    132   // H tile stride (128 + 4) -> row stride 264B = 66 banks = 2 mod 32

typedef __bf16 bf16x8 __attribute__((ext_vector_type(8)));
typedef float  f32x4  __attribute__((ext_vector_type(4)));

__device__ __forceinline__ unsigned short f2bf(float f) {
    union { float f; unsigned u; } v; v.f = f;
    unsigned u = v.u;
    u += 0x7FFFu + ((u >> 16) & 1u);   // round-to-nearest-even
    return (unsigned short)(u >> 16);
}

// Convert W1 [320][128] -> W1^T bf16 [128][320]; W2 [128][128] -> W2^T bf16 [128][128]
__global__ void prep_weights(const float* __restrict__ W1,
                             const float* __restrict__ W2,
                             unsigned short* __restrict__ w1t,
                             unsigned short* __restrict__ w2t) {
    int idx = blockIdx.x * blockDim.x + threadIdx.x;
    if (idx < N_H * N_IN) {
        int n = idx / N_IN, k = idx % N_IN;
        w1t[idx] = f2bf(W1[(size_t)k * N_H + n]);
    } else if (idx < N_H * N_IN + N_H * N_H) {
        int j = idx - N_H * N_IN;
        int n = j / N_H, k = j % N_H;
        w2t[j] = f2bf(W2[(size_t)k * N_H + n]);
    }
}

// One block = 4 independent waves; each wave owns 16 edges end-to-end.
// No __syncthreads. A-fragments loaded straight from global (gather),
// only a 4.2KB/wave LDS buffer for the H transpose between GEMM1 and GEMM2.
__global__ __launch_bounds__(256, 4)
void edge_mlp(const float* __restrict__ ninv, const float* __restrict__ ef,
              const int* __restrict__ ei,
              const unsigned short* __restrict__ w1t,
              const unsigned short* __restrict__ w2t,
              const float* __restrict__ b1, const float* __restrict__ b2,
              const float* __restrict__ gamma, const float* __restrict__ beta,
              float* __restrict__ out, int E) {
    __shared__ __align__(16) unsigned short hlds[4][16 * HS];  // 16896 B

    const int tid  = threadIdx.x;
    const int wv   = tid >> 6;
    const int lane = tid & 63;
    const int lr   = lane & 15;        // A row within wave tile / B col / D col
    const int lkg  = lane >> 4;        // k-group 0..3
    const int lk   = lkg * 8;          // k elem offset within 32-step

    const int er = (int)blockIdx.x * 64 + wv * 16 + lr;  // this lane's edge row
    const int e  = er < E ? er : E - 1;
    const int s  = ei[e];
    const int d  = ei[(size_t)E + e];

    // ---- GEMM1: [16 x 320] x [320 x 128], A direct from global ----
    f32x4 acc[8] = {};
    #pragma unroll
    for (int ks = 0; ks < N_IN / 32; ++ks) {
        const float* ap;
        if (ks < 3)      ap = ninv + (size_t)s * N_INV + ks * 32;
        else if (ks < 6) ap = ninv + (size_t)d * N_INV + (ks - 3) * 32;
        else             ap = ef + (size_t)e * N_H + (ks - 6) * 32;
        float4 v0 = *(const float4*)(ap + lk);
        float4 v1 = *(const float4*)(ap + lk + 4);
        union { unsigned short us[8]; bf16x8 b; } ua;
        ua.us[0] = f2bf(v0.x); ua.us[1] = f2bf(v0.y);
        ua.us[2] = f2bf(v0.z); ua.us[3] = f2bf(v0.w);
        ua.us[4] = f2bf(v1.x); ua.us[5] = f2bf(v1.y);
        ua.us[6] = f2bf(v1.z); ua.us[7] = f2bf(v1.w);
        #pragma unroll
        for (int nt = 0; nt < 8; ++nt) {
            bf16x8 b = *(const bf16x8*)(w1t + (size_t)(nt * 16 + lr) * N_IN + ks * 32 + lk);
            acc[nt] = __builtin_amdgcn_mfma_f32_16x16x32_bf16(ua.b, b, acc[nt], 0, 0, 0);
        }
    }

    // ---- bias + ReLU -> bf16 H tile in this wave's LDS region ----
    // C/D layout: col = lane&15, row = (lane>>4)*4 + i   [m89]
    const int qr = lkg * 4;
    unsigned short* hw = hlds[wv];
    #pragma unroll
    for (int nt = 0; nt < 8; ++nt) {
        float bb = b1[nt * 16 + lr];
        #pragma unroll
        for (int i = 0; i < 4; ++i) {
            float v = acc[nt][i] + bb;
            v = v > 0.0f ? v : 0.0f;
            hw[(qr + i) * HS + nt * 16 + lr] = f2bf(v);
        }
    }
    // same-wave LDS RAW: DS ops execute in order within a wave; keep the
    // compiler from reordering reads above the writes.
    __builtin_amdgcn_wave_barrier();

    // ---- GEMM2: [16 x 128] x [128 x 128] ----
    f32x4 acc2[8] = {};
    const unsigned short* hrow = &hw[lr * HS];
    #pragma unroll
    for (int ks = 0; ks < N_H / 32; ++ks) {
        bf16x8 a = *(const bf16x8*)(hrow + ks * 32 + lk);
        #pragma unroll
        for (int nt = 0; nt < 8; ++nt) {
            bf16x8 b = *(const bf16x8*)(w2t + (size_t)(nt * 16 + lr) * N_H + ks * 32 + lk);
            acc2[nt] = __builtin_amdgcn_mfma_f32_16x16x32_bf16(a, b, acc2[nt], 0, 0, 0);
        }
    }

    // ---- bias + LayerNorm + residual + store ----
    float vals[8][4];
    float s1[4] = {0.f, 0.f, 0.f, 0.f};
    float s2[4] = {0.f, 0.f, 0.f, 0.f};
    #pragma unroll
    for (int nt = 0; nt < 8; ++nt) {
        float bb = b2[nt * 16 + lr];
        #pragma unroll
        for (int i = 0; i < 4; ++i) {
            float v = acc2[nt][i] + bb;
            vals[nt][i] = v;
            s1[i] += v;
            s2[i] += v * v;
        }
    }
    #pragma unroll
    for (int m = 1; m < 16; m <<= 1) {
        #pragma unroll
        for (int i = 0; i < 4; ++i) {
            s1[i] += __shfl_xor(s1[i], m);
            s2[i] += __shfl_xor(s2[i], m);
        }
    }
    float mu[4], rs[4];
    #pragma unroll
    for (int i = 0; i < 4; ++i) {
        mu[i] = s1[i] * (1.0f / 128.0f);
        float var = s2[i] * (1.0f / 128.0f) - mu[i] * mu[i];
        rs[i] = rsqrtf(var + 1e-5f);
    }

    const int rbase = (int)blockIdx.x * 64 + wv * 16 + qr;
    #pragma unroll
    for (int nt = 0; nt < 8; ++nt) {
        int c = nt * 16 + lr;
        float g  = gamma[c];
        float bt = beta[c];
        #pragma unroll
        for (int i = 0; i < 4; ++i) {
            int eo = rbase + i;
            if (eo < E) {
                float r = ef[(size_t)eo * N_H + c];
                out[(size_t)eo * N_H + c] = (vals[nt][i] - mu[i]) * rs[i] * g + bt + r;
            }
        }
    }
}

extern "C" void kernel_launch(void* const* d_in, const int* in_sizes, int n_in,
                              void* d_out, int out_size, void* d_ws, size_t ws_size,
                              hipStream_t stream) {
    const float* ninv = (const float*)d_in[0];
    const float* ef   = (const float*)d_in[1];
    const int*   ei   = (const int*)d_in[2];
    const float* W1   = (const float*)d_in[3];
    const float* b1   = (const float*)d_in[4];
    const float* W2   = (const float*)d_in[5];
    const float* b2   = (const float*)d_in[6];
    const float* g    = (const float*)d_in[7];
    const float* bt   = (const float*)d_in[8];
    float* out = (float*)d_out;

    const int E = in_sizes[1] / N_H;

    unsigned short* w1t = (unsigned short*)d_ws;             // 128*320 bf16
    unsigned short* w2t = w1t + N_H * N_IN;                  // 128*128 bf16

    int prep_total = N_H * N_IN + N_H * N_H;
    prep_weights<<<(prep_total + 255) / 256, 256, 0, stream>>>(W1, W2, w1t, w2t);

    int nblk = (E + 63) / 64;
    edge_mlp<<<nblk, 256, 0, stream>>>(ninv, ef, ei, w1t, w2t, b1, b2, g, bt, out, E);
}

// Round 3
// 657.796 us; speedup vs baseline: 1.7344x; 1.2422x over previous
//
#include <hip/hip_runtime.h>
#include <stdint.h>

#define N_H   128
#define N_INV 96
#define N_IN  320
#define HS    132   // H tile stride (128 + 4) -> row stride 264B, measured 0 bank conflicts
#define TILES 2
#define EPW   (TILES * 16)   // 32 edges per wave
#define EPB   (EPW * 4)      // 128 edges per block

typedef __bf16 bf16x8 __attribute__((ext_vector_type(8)));
typedef float  f32x4  __attribute__((ext_vector_type(4)));

__device__ __forceinline__ unsigned short f2bf(float f) {
    union { float f; unsigned u; } v; v.f = f;
    unsigned u = v.u;
    u += 0x7FFFu + ((u >> 16) & 1u);   // round-to-nearest-even
    return (unsigned short)(u >> 16);
}

// Convert W1 [320][128] -> W1^T bf16 [128][320]; W2 [128][128] -> W2^T bf16 [128][128]
__global__ void prep_weights(const float* __restrict__ W1,
                             const float* __restrict__ W2,
                             unsigned short* __restrict__ w1t,
                             unsigned short* __restrict__ w2t) {
    int idx = blockIdx.x * blockDim.x + threadIdx.x;
    if (idx < N_H * N_IN) {
        int n = idx / N_IN, k = idx % N_IN;
        w1t[idx] = f2bf(W1[(size_t)k * N_H + n]);
    } else if (idx < N_H * N_IN + N_H * N_H) {
        int j = idx - N_H * N_IN;
        int n = j / N_H, k = j % N_H;
        w2t[j] = f2bf(W2[(size_t)k * N_H + n]);
    }
}

// 4 independent waves per block; each wave owns 32 edges (2 MFMA row-tiles).
// B-fragments (weights) are loaded once per ks-step and shared across both
// tiles, halving weight L2 traffic and doubling MFMA per load.
__global__ __launch_bounds__(256, 3)
void edge_mlp(const float* __restrict__ ninv, const float* __restrict__ ef,
              const int* __restrict__ ei,
              const unsigned short* __restrict__ w1t,
              const unsigned short* __restrict__ w2t,
              const float* __restrict__ b1, const float* __restrict__ b2,
              const float* __restrict__ gamma, const float* __restrict__ beta,
              float* __restrict__ out, int E) {
    __shared__ __align__(16) unsigned short hlds[4][TILES][16 * HS];  // 33792 B

    const int tid  = threadIdx.x;
    const int wv   = tid >> 6;
    const int lane = tid & 63;
    const int lr   = lane & 15;        // A row within tile / B col / D col
    const int lkg  = lane >> 4;        // k-group 0..3
    const int lk   = lkg * 8;          // k elem offset within 32-step

    const int ebase = (int)blockIdx.x * EPB + wv * EPW;

    int e[TILES], s[TILES], d[TILES];
    #pragma unroll
    for (int t = 0; t < TILES; ++t) {
        int er = ebase + t * 16 + lr;
        e[t] = er < E ? er : E - 1;
        s[t] = ei[e[t]];
        d[t] = ei[(size_t)E + e[t]];
    }

    // ---- GEMM1: per tile [16 x 320] x shared [320 x 128] ----
    f32x4 acc[TILES][8] = {};
    #pragma unroll
    for (int ks = 0; ks < N_IN / 32; ++ks) {
        bf16x8 bfr[8];
        #pragma unroll
        for (int nt = 0; nt < 8; ++nt)
            bfr[nt] = *(const bf16x8*)(w1t + (size_t)(nt * 16 + lr) * N_IN + ks * 32 + lk);
        #pragma unroll
        for (int t = 0; t < TILES; ++t) {
            const float* ap;
            if (ks < 3)      ap = ninv + (size_t)s[t] * N_INV + ks * 32;
            else if (ks < 6) ap = ninv + (size_t)d[t] * N_INV + (ks - 3) * 32;
            else             ap = ef + (size_t)e[t] * N_H + (ks - 6) * 32;
            float4 v0 = *(const float4*)(ap + lk);
            float4 v1 = *(const float4*)(ap + lk + 4);
            union { unsigned short us[8]; bf16x8 b; } ua;
            ua.us[0] = f2bf(v0.x); ua.us[1] = f2bf(v0.y);
            ua.us[2] = f2bf(v0.z); ua.us[3] = f2bf(v0.w);
            ua.us[4] = f2bf(v1.x); ua.us[5] = f2bf(v1.y);
            ua.us[6] = f2bf(v1.z); ua.us[7] = f2bf(v1.w);
            #pragma unroll
            for (int nt = 0; nt < 8; ++nt)
                acc[t][nt] = __builtin_amdgcn_mfma_f32_16x16x32_bf16(ua.b, bfr[nt], acc[t][nt], 0, 0, 0);
        }
    }

    // ---- bias + ReLU -> bf16 H tiles in this wave's LDS region ----
    // C/D layout: col = lane&15, row = (lane>>4)*4 + i   [m89]
    const int qr = lkg * 4;
    #pragma unroll
    for (int t = 0; t < TILES; ++t) {
        unsigned short* hw = hlds[wv][t];
        #pragma unroll
        for (int nt = 0; nt < 8; ++nt) {
            float bb = b1[nt * 16 + lr];
            #pragma unroll
            for (int i = 0; i < 4; ++i) {
                float v = acc[t][nt][i] + bb;
                v = v > 0.0f ? v : 0.0f;
                hw[(qr + i) * HS + nt * 16 + lr] = f2bf(v);
            }
        }
    }
    // same-wave LDS RAW ordering
    __builtin_amdgcn_wave_barrier();

    // ---- GEMM2: per tile [16 x 128] x shared [128 x 128] ----
    f32x4 acc2[TILES][8] = {};
    #pragma unroll
    for (int ks = 0; ks < N_H / 32; ++ks) {
        bf16x8 bfr[8];
        #pragma unroll
        for (int nt = 0; nt < 8; ++nt)
            bfr[nt] = *(const bf16x8*)(w2t + (size_t)(nt * 16 + lr) * N_H + ks * 32 + lk);
        #pragma unroll
        for (int t = 0; t < TILES; ++t) {
            bf16x8 a = *(const bf16x8*)(&hlds[wv][t][lr * HS + ks * 32 + lk]);
            #pragma unroll
            for (int nt = 0; nt < 8; ++nt)
                acc2[t][nt] = __builtin_amdgcn_mfma_f32_16x16x32_bf16(a, bfr[nt], acc2[t][nt], 0, 0, 0);
        }
    }

    // ---- per tile: bias + LayerNorm + residual + store ----
    #pragma unroll
    for (int t = 0; t < TILES; ++t) {
        float vals[8][4];
        float s1[4] = {0.f, 0.f, 0.f, 0.f};
        float s2[4] = {0.f, 0.f, 0.f, 0.f};
        #pragma unroll
        for (int nt = 0; nt < 8; ++nt) {
            float bb = b2[nt * 16 + lr];
            #pragma unroll
            for (int i = 0; i < 4; ++i) {
                float v = acc2[t][nt][i] + bb;
                vals[nt][i] = v;
                s1[i] += v;
                s2[i] += v * v;
            }
        }
        #pragma unroll
        for (int m = 1; m < 16; m <<= 1) {
            #pragma unroll
            for (int i = 0; i < 4; ++i) {
                s1[i] += __shfl_xor(s1[i], m);
                s2[i] += __shfl_xor(s2[i], m);
            }
        }
        float mu[4], rs[4];
        #pragma unroll
        for (int i = 0; i < 4; ++i) {
            mu[i] = s1[i] * (1.0f / 128.0f);
            float var = s2[i] * (1.0f / 128.0f) - mu[i] * mu[i];
            rs[i] = rsqrtf(var + 1e-5f);
        }

        const int rbase = ebase + t * 16 + qr;
        #pragma unroll
        for (int nt = 0; nt < 8; ++nt) {
            int c = nt * 16 + lr;
            float g  = gamma[c];
            float bt = beta[c];
            #pragma unroll
            for (int i = 0; i < 4; ++i) {
                int eo = rbase + i;
                if (eo < E) {
                    float r = ef[(size_t)eo * N_H + c];
                    out[(size_t)eo * N_H + c] = (vals[nt][i] - mu[i]) * rs[i] * g + bt + r;
                }
            }
        }
    }
}

extern "C" void kernel_launch(void* const* d_in, const int* in_sizes, int n_in,
                              void* d_out, int out_size, void* d_ws, size_t ws_size,
                              hipStream_t stream) {
    const float* ninv = (const float*)d_in[0];
    const float* ef   = (const float*)d_in[1];
    const int*   ei   = (const int*)d_in[2];
    const float* W1   = (const float*)d_in[3];
    const float* b1   = (const float*)d_in[4];
    const float* W2   = (const float*)d_in[5];
    const float* b2   = (const float*)d_in[6];
    const float* g    = (const float*)d_in[7];
    const float* bt   = (const float*)d_in[8];
    float* out = (float*)d_out;

    const int E = in_sizes[1] / N_H;

    unsigned short* w1t = (unsigned short*)d_ws;             // 128*320 bf16
    unsigned short* w2t = w1t + N_H * N_IN;                  // 128*128 bf16

    int prep_total = N_H * N_IN + N_H * N_H;
    prep_weights<<<(prep_total + 255) / 256, 256, 0, stream>>>(W1, W2, w1t, w2t);

    int nblk = (E + EPB - 1) / EPB;
    edge_mlp<<<nblk, 256, 0, stream>>>(ninv, ef, ei, w1t, w2t, b1, b2, g, bt, out, E);
}

// Round 4
// 505.632 us; speedup vs baseline: 2.2563x; 1.3009x over previous
//
#include <hip/hip_runtime.h>
#include <stdint.h>

#define N_H   128
#define N_INV 96
#define N_IN  320
#define HS    132   // H tile stride (128 + 4) -> measured 0 bank conflicts
#define TILES 4
#define EPW   (TILES * 16)   // 64 edges per wave
#define EPB   (EPW * 4)      // 256 edges per block

#define KS1   (N_IN / 32)    // 10
#define KS2   (N_H / 32)     // 4

typedef __bf16 bf16x8 __attribute__((ext_vector_type(8)));
typedef float  f32x4  __attribute__((ext_vector_type(4)));

__device__ __forceinline__ unsigned short f2bf(float f) {
    union { float f; unsigned u; } v; v.f = f;
    unsigned u = v.u;
    u += 0x7FFFu + ((u >> 16) & 1u);   // round-to-nearest-even
    return (unsigned short)(u >> 16);
}

// Pack weights in MFMA-fragment order so each wave's fragment load is one
// contiguous, fully-coalesced 1KB burst (base + lane*16B):
//   w1p[ks][nt][lane][j] = W1[k = ks*32 + (lane>>4)*8 + j][n = nt*16 + (lane&15)]
//   w2p likewise from W2.  w1p: 10*8*64*8 = 40960 elems; w2p: 4*8*64*8 = 16384.
__global__ void prep_weights(const float* __restrict__ W1,
                             const float* __restrict__ W2,
                             unsigned short* __restrict__ w1p,
                             unsigned short* __restrict__ w2p) {
    int idx = blockIdx.x * blockDim.x + threadIdx.x;
    if (idx < KS1 * 8 * 64 * 8) {
        int j = idx & 7, lane = (idx >> 3) & 63, nt = (idx >> 9) & 7, ks = idx >> 12;
        int k = ks * 32 + (lane >> 4) * 8 + j;
        int n = nt * 16 + (lane & 15);
        w1p[idx] = f2bf(W1[(size_t)k * N_H + n]);
    } else {
        int r = idx - KS1 * 8 * 64 * 8;
        if (r < KS2 * 8 * 64 * 8) {
            int j = r & 7, lane = (r >> 3) & 63, nt = (r >> 9) & 7, ks = r >> 12;
            int k = ks * 32 + (lane >> 4) * 8 + j;
            int n = nt * 16 + (lane & 15);
            w2p[r] = f2bf(W2[(size_t)k * N_H + n]);
        }
    }
}

// 4 independent waves per block; each wave owns 64 edges (4 MFMA row-tiles).
// Weight fragments loaded once per ks-step feed 4 tiles' MFMAs (32 MFMA per
// 8 weight loads), quartering per-CU weight traffic vs 1 tile/wave.
__global__ __launch_bounds__(256, 2)
void edge_mlp(const float* __restrict__ ninv, const float* __restrict__ ef,
              const int* __restrict__ ei,
              const unsigned short* __restrict__ w1p,
              const unsigned short* __restrict__ w2p,
              const float* __restrict__ b1, const float* __restrict__ b2,
              const float* __restrict__ gamma, const float* __restrict__ beta,
              float* __restrict__ out, int E) {
    __shared__ __align__(16) unsigned short hlds[4][TILES][16 * HS];  // 67584 B

    const int tid  = threadIdx.x;
    const int wv   = tid >> 6;
    const int lane = tid & 63;
    const int lr   = lane & 15;        // A row within tile / B col / D col
    const int lkg  = lane >> 4;        // k-group 0..3
    const int lk   = lkg * 8;          // k elem offset within 32-step

    const int ebase = (int)blockIdx.x * EPB + wv * EPW;

    int e[TILES], s[TILES], d[TILES];
    #pragma unroll
    for (int t = 0; t < TILES; ++t) {
        int er = ebase + t * 16 + lr;
        e[t] = er < E ? er : E - 1;
        s[t] = ei[e[t]];
        d[t] = ei[(size_t)E + e[t]];
    }

    // ---- GEMM1: per tile [16 x 320] x shared [320 x 128] ----
    f32x4 acc[TILES][8] = {};
    #pragma unroll
    for (int ks = 0; ks < KS1; ++ks) {
        bf16x8 bfr[8];
        #pragma unroll
        for (int nt = 0; nt < 8; ++nt)
            bfr[nt] = *(const bf16x8*)(w1p + ((ks * 8 + nt) << 9) + (lane << 3));
        #pragma unroll
        for (int t = 0; t < TILES; ++t) {
            const float* ap;
            if (ks < 3)      ap = ninv + (size_t)s[t] * N_INV + ks * 32;
            else if (ks < 6) ap = ninv + (size_t)d[t] * N_INV + (ks - 3) * 32;
            else             ap = ef + (size_t)e[t] * N_H + (ks - 6) * 32;
            float4 v0 = *(const float4*)(ap + lk);
            float4 v1 = *(const float4*)(ap + lk + 4);
            union { unsigned short us[8]; bf16x8 b; } ua;
            ua.us[0] = f2bf(v0.x); ua.us[1] = f2bf(v0.y);
            ua.us[2] = f2bf(v0.z); ua.us[3] = f2bf(v0.w);
            ua.us[4] = f2bf(v1.x); ua.us[5] = f2bf(v1.y);
            ua.us[6] = f2bf(v1.z); ua.us[7] = f2bf(v1.w);
            #pragma unroll
            for (int nt = 0; nt < 8; ++nt)
                acc[t][nt] = __builtin_amdgcn_mfma_f32_16x16x32_bf16(ua.b, bfr[nt], acc[t][nt], 0, 0, 0);
        }
    }

    // ---- bias + ReLU -> bf16 H tiles in this wave's LDS region ----
    // C/D layout: col = lane&15, row = (lane>>4)*4 + i   [m89]
    const int qr = lkg * 4;
    #pragma unroll
    for (int t = 0; t < TILES; ++t) {
        unsigned short* hw = hlds[wv][t];
        #pragma unroll
        for (int nt = 0; nt < 8; ++nt) {
            float bb = b1[nt * 16 + lr];
            #pragma unroll
            for (int i = 0; i < 4; ++i) {
                float v = acc[t][nt][i] + bb;
                v = v > 0.0f ? v : 0.0f;
                hw[(qr + i) * HS + nt * 16 + lr] = f2bf(v);
            }
        }
    }
    // same-wave LDS RAW ordering
    __builtin_amdgcn_wave_barrier();

    // ---- GEMM2: per tile [16 x 128] x shared [128 x 128] ----
    f32x4 acc2[TILES][8] = {};
    #pragma unroll
    for (int ks = 0; ks < KS2; ++ks) {
        bf16x8 bfr[8];
        #pragma unroll
        for (int nt = 0; nt < 8; ++nt)
            bfr[nt] = *(const bf16x8*)(w2p + ((ks * 8 + nt) << 9) + (lane << 3));
        #pragma unroll
        for (int t = 0; t < TILES; ++t) {
            bf16x8 a = *(const bf16x8*)(&hlds[wv][t][lr * HS + ks * 32 + lk]);
            #pragma unroll
            for (int nt = 0; nt < 8; ++nt)
                acc2[t][nt] = __builtin_amdgcn_mfma_f32_16x16x32_bf16(a, bfr[nt], acc2[t][nt], 0, 0, 0);
        }
    }

    // ---- per tile: bias + LayerNorm + residual + store ----
    #pragma unroll
    for (int t = 0; t < TILES; ++t) {
        float vals[8][4];
        float s1[4] = {0.f, 0.f, 0.f, 0.f};
        float s2[4] = {0.f, 0.f, 0.f, 0.f};
        #pragma unroll
        for (int nt = 0; nt < 8; ++nt) {
            float bb = b2[nt * 16 + lr];
            #pragma unroll
            for (int i = 0; i < 4; ++i) {
                float v = acc2[t][nt][i] + bb;
                vals[nt][i] = v;
                s1[i] += v;
                s2[i] += v * v;
            }
        }
        #pragma unroll
        for (int m = 1; m < 16; m <<= 1) {
            #pragma unroll
            for (int i = 0; i < 4; ++i) {
                s1[i] += __shfl_xor(s1[i], m);
                s2[i] += __shfl_xor(s2[i], m);
            }
        }
        float mu[4], rs[4];
        #pragma unroll
        for (int i = 0; i < 4; ++i) {
            mu[i] = s1[i] * (1.0f / 128.0f);
            float var = s2[i] * (1.0f / 128.0f) - mu[i] * mu[i];
            rs[i] = rsqrtf(var + 1e-5f);
        }

        const int rbase = ebase + t * 16 + qr;
        #pragma unroll
        for (int nt = 0; nt < 8; ++nt) {
            int c = nt * 16 + lr;
            float g  = gamma[c];
            float bt = beta[c];
            #pragma unroll
            for (int i = 0; i < 4; ++i) {
                int eo = rbase + i;
                if (eo < E) {
                    float r = ef[(size_t)eo * N_H + c];
                    out[(size_t)eo * N_H + c] = (vals[nt][i] - mu[i]) * rs[i] * g + bt + r;
                }
            }
        }
    }
}

extern "C" void kernel_launch(void* const* d_in, const int* in_sizes, int n_in,
                              void* d_out, int out_size, void* d_ws, size_t ws_size,
                              hipStream_t stream) {
    const float* ninv = (const float*)d_in[0];
    const float* ef   = (const float*)d_in[1];
    const int*   ei   = (const int*)d_in[2];
    const float* W1   = (const float*)d_in[3];
    const float* b1   = (const float*)d_in[4];
    const float* W2   = (const float*)d_in[5];
    const float* b2   = (const float*)d_in[6];
    const float* g    = (const float*)d_in[7];
    const float* bt   = (const float*)d_in[8];
    float* out = (float*)d_out;

    const int E = in_sizes[1] / N_H;

    unsigned short* w1p = (unsigned short*)d_ws;             // 40960 bf16
    unsigned short* w2p = w1p + KS1 * 8 * 64 * 8;            // 16384 bf16

    int prep_total = (KS1 + KS2) * 8 * 64 * 8;
    prep_weights<<<(prep_total + 255) / 256, 256, 0, stream>>>(W1, W2, w1p, w2p);

    int nblk = (E + EPB - 1) / EPB;
    edge_mlp<<<nblk, 256, 0, stream>>>(ninv, ef, ei, w1p, w2p, b1, b2, g, bt, out, E);
}

// Round 5
// 482.047 us; speedup vs baseline: 2.3667x; 1.0489x over previous
//
#include <hip/hip_runtime.h>
#include <stdint.h>

#define N_H   128
#define N_INV 96
#define N_IN  320
#define HS    132   // H tile stride (128 + 4) -> measured 0 bank conflicts
#define TILES 3
#define EPW   (TILES * 16)   // 48 edges per wave
#define EPB   (EPW * 4)      // 192 edges per block

#define KS1   (N_IN / 32)    // 10
#define KS2   (N_H / 32)     // 4

typedef __bf16 bf16x8 __attribute__((ext_vector_type(8)));
typedef float  f32x4  __attribute__((ext_vector_type(4)));

__device__ __forceinline__ unsigned short f2bf(float f) {
    union { float f; unsigned u; } v; v.f = f;
    unsigned u = v.u;
    u += 0x7FFFu + ((u >> 16) & 1u);   // round-to-nearest-even
    return (unsigned short)(u >> 16);
}

// Pack weights in MFMA-fragment order so each wave's fragment load is one
// contiguous, fully-coalesced 1KB burst (base + lane*16B):
//   w1p[ks][nt][lane][j] = W1[k = ks*32 + (lane>>4)*8 + j][n = nt*16 + (lane&15)]
__global__ void prep_weights(const float* __restrict__ W1,
                             const float* __restrict__ W2,
                             unsigned short* __restrict__ w1p,
                             unsigned short* __restrict__ w2p) {
    int idx = blockIdx.x * blockDim.x + threadIdx.x;
    if (idx < KS1 * 8 * 64 * 8) {
        int j = idx & 7, lane = (idx >> 3) & 63, nt = (idx >> 9) & 7, ks = idx >> 12;
        int k = ks * 32 + (lane >> 4) * 8 + j;
        int n = nt * 16 + (lane & 15);
        w1p[idx] = f2bf(W1[(size_t)k * N_H + n]);
    } else {
        int r = idx - KS1 * 8 * 64 * 8;
        if (r < KS2 * 8 * 64 * 8) {
            int j = r & 7, lane = (r >> 3) & 63, nt = (r >> 9) & 7, ks = r >> 12;
            int k = ks * 32 + (lane >> 4) * 8 + j;
            int n = nt * 16 + (lane & 15);
            w2p[r] = f2bf(W2[(size_t)k * N_H + n]);
        }
    }
}

// 4 independent waves per block; each wave owns 48 edges (3 MFMA row-tiles).
// TILES=3 balances weight-load amortization (shared B-fragments across
// tiles) against register pressure: acc = 96 AGPR + ~70 VGPR fits 3
// waves/SIMD (total <= 512/3), vs TILES=4's 128 AGPR forcing 2/SIMD.
__global__ __launch_bounds__(256, 3)
void edge_mlp(const float* __restrict__ ninv, const float* __restrict__ ef,
              const int* __restrict__ ei,
              const unsigned short* __restrict__ w1p,
              const unsigned short* __restrict__ w2p,
              const float* __restrict__ b1, const float* __restrict__ b2,
              const float* __restrict__ gamma, const float* __restrict__ beta,
              float* __restrict__ out, int E) {
    __shared__ __align__(16) unsigned short hlds[4][TILES][16 * HS];  // 50688 B

    const int tid  = threadIdx.x;
    const int wv   = tid >> 6;
    const int lane = tid & 63;
    const int lr   = lane & 15;        // A row within tile / B col / D col
    const int lkg  = lane >> 4;        // k-group 0..3
    const int lk   = lkg * 8;          // k elem offset within 32-step

    const int ebase = (int)blockIdx.x * EPB + wv * EPW;

    int e[TILES], s[TILES], d[TILES];
    #pragma unroll
    for (int t = 0; t < TILES; ++t) {
        int er = ebase + t * 16 + lr;
        e[t] = er < E ? er : E - 1;
        s[t] = ei[e[t]];
        d[t] = ei[(size_t)E + e[t]];
    }

    // ---- GEMM1: per tile [16 x 320] x shared [320 x 128] ----
    f32x4 acc[TILES][8] = {};
    #pragma unroll
    for (int ks = 0; ks < KS1; ++ks) {
        bf16x8 bfr[8];
        #pragma unroll
        for (int nt = 0; nt < 8; ++nt)
            bfr[nt] = *(const bf16x8*)(w1p + ((ks * 8 + nt) << 9) + (lane << 3));
        #pragma unroll
        for (int t = 0; t < TILES; ++t) {
            const float* ap;
            if (ks < 3)      ap = ninv + (size_t)s[t] * N_INV + ks * 32;
            else if (ks < 6) ap = ninv + (size_t)d[t] * N_INV + (ks - 3) * 32;
            else             ap = ef + (size_t)e[t] * N_H + (ks - 6) * 32;
            float4 v0 = *(const float4*)(ap + lk);
            float4 v1 = *(const float4*)(ap + lk + 4);
            union { unsigned short us[8]; bf16x8 b; } ua;
            ua.us[0] = f2bf(v0.x); ua.us[1] = f2bf(v0.y);
            ua.us[2] = f2bf(v0.z); ua.us[3] = f2bf(v0.w);
            ua.us[4] = f2bf(v1.x); ua.us[5] = f2bf(v1.y);
            ua.us[6] = f2bf(v1.z); ua.us[7] = f2bf(v1.w);
            #pragma unroll
            for (int nt = 0; nt < 8; ++nt)
                acc[t][nt] = __builtin_amdgcn_mfma_f32_16x16x32_bf16(ua.b, bfr[nt], acc[t][nt], 0, 0, 0);
        }
    }

    // ---- bias + ReLU -> bf16 H tiles in this wave's LDS region ----
    // C/D layout: col = lane&15, row = (lane>>4)*4 + i   [m89]
    const int qr = lkg * 4;
    #pragma unroll
    for (int t = 0; t < TILES; ++t) {
        unsigned short* hw = hlds[wv][t];
        #pragma unroll
        for (int nt = 0; nt < 8; ++nt) {
            float bb = b1[nt * 16 + lr];
            #pragma unroll
            for (int i = 0; i < 4; ++i) {
                float v = acc[t][nt][i] + bb;
                v = v > 0.0f ? v : 0.0f;
                hw[(qr + i) * HS + nt * 16 + lr] = f2bf(v);
            }
        }
    }
    // same-wave LDS RAW ordering
    __builtin_amdgcn_wave_barrier();

    // ---- GEMM2: per tile [16 x 128] x shared [128 x 128] ----
    f32x4 acc2[TILES][8] = {};
    #pragma unroll
    for (int ks = 0; ks < KS2; ++ks) {
        bf16x8 bfr[8];
        #pragma unroll
        for (int nt = 0; nt < 8; ++nt)
            bfr[nt] = *(const bf16x8*)(w2p + ((ks * 8 + nt) << 9) + (lane << 3));
        #pragma unroll
        for (int t = 0; t < TILES; ++t) {
            bf16x8 a = *(const bf16x8*)(&hlds[wv][t][lr * HS + ks * 32 + lk]);
            #pragma unroll
            for (int nt = 0; nt < 8; ++nt)
                acc2[t][nt] = __builtin_amdgcn_mfma_f32_16x16x32_bf16(a, bfr[nt], acc2[t][nt], 0, 0, 0);
        }
    }

    // ---- per tile: bias + LayerNorm + residual + store ----
    #pragma unroll
    for (int t = 0; t < TILES; ++t) {
        float vals[8][4];
        float s1[4] = {0.f, 0.f, 0.f, 0.f};
        float s2[4] = {0.f, 0.f, 0.f, 0.f};
        #pragma unroll
        for (int nt = 0; nt < 8; ++nt) {
            float bb = b2[nt * 16 + lr];
            #pragma unroll
            for (int i = 0; i < 4; ++i) {
                float v = acc2[t][nt][i] + bb;
                vals[nt][i] = v;
                s1[i] += v;
                s2[i] += v * v;
            }
        }
        #pragma unroll
        for (int m = 1; m < 16; m <<= 1) {
            #pragma unroll
            for (int i = 0; i < 4; ++i) {
                s1[i] += __shfl_xor(s1[i], m);
                s2[i] += __shfl_xor(s2[i], m);
            }
        }
        float mu[4], rs[4];
        #pragma unroll
        for (int i = 0; i < 4; ++i) {
            mu[i] = s1[i] * (1.0f / 128.0f);
            float var = s2[i] * (1.0f / 128.0f) - mu[i] * mu[i];
            rs[i] = rsqrtf(var + 1e-5f);
        }

        const int rbase = ebase + t * 16 + qr;
        #pragma unroll
        for (int nt = 0; nt < 8; ++nt) {
            int c = nt * 16 + lr;
            float g  = gamma[c];
            float bt = beta[c];
            #pragma unroll
            for (int i = 0; i < 4; ++i) {
                int eo = rbase + i;
                if (eo < E) {
                    float r = ef[(size_t)eo * N_H + c];
                    out[(size_t)eo * N_H + c] = (vals[nt][i] - mu[i]) * rs[i] * g + bt + r;
                }
            }
        }
    }
}

extern "C" void kernel_launch(void* const* d_in, const int* in_sizes, int n_in,
                              void* d_out, int out_size, void* d_ws, size_t ws_size,
                              hipStream_t stream) {
    const float* ninv = (const float*)d_in[0];
    const float* ef   = (const float*)d_in[1];
    const int*   ei   = (const int*)d_in[2];
    const float* W1   = (const float*)d_in[3];
    const float* b1   = (const float*)d_in[4];
    const float* W2   = (const float*)d_in[5];
    const float* b2   = (const float*)d_in[6];
    const float* g    = (const float*)d_in[7];
    const float* bt   = (const float*)d_in[8];
    float* out = (float*)d_out;

    const int E = in_sizes[1] / N_H;

    unsigned short* w1p = (unsigned short*)d_ws;             // 40960 bf16
    unsigned short* w2p = w1p + KS1 * 8 * 64 * 8;            // 16384 bf16

    int prep_total = (KS1 + KS2) * 8 * 64 * 8;
    prep_weights<<<(prep_total + 255) / 256, 256, 0, stream>>>(W1, W2, w1p, w2p);

    int nblk = (E + EPB - 1) / EPB;
    edge_mlp<<<nblk, 256, 0, stream>>>(ninv, ef, ei, w1p, w2p, b1, b2, g, bt, out, E);
}

// Round 6
// 373.223 us; speedup vs baseline: 3.0568x; 1.2916x over previous
//
#include <hip/hip_runtime.h>
#include <stdint.h>

#define N_H   128
#define N_INV 96
#define N_IN  320
#define HS    132   // H tile stride (128 + 4) -> measured 0 bank conflicts
#define TILES 2
#define EPW   (TILES * 16)   // 32 edges per wave
#define EPB   (EPW * 4)      // 128 edges per block

#define KS1   (N_IN / 32)    // 10
#define KS2   (N_H / 32)     // 4

typedef __bf16 bf16x8 __attribute__((ext_vector_type(8)));
typedef float  f32x4  __attribute__((ext_vector_type(4)));

__device__ __forceinline__ unsigned short f2bf(float f) {
    union { float f; unsigned u; } v; v.f = f;
    unsigned u = v.u;
    u += 0x7FFFu + ((u >> 16) & 1u);   // round-to-nearest-even
    return (unsigned short)(u >> 16);
}

// Pack weights in MFMA-fragment order: one contiguous 1KB burst per fragment.
//   w1p[ks][nt][lane][j] = W1[k = ks*32 + (lane>>4)*8 + j][n = nt*16 + (lane&15)]
__global__ void prep_weights(const float* __restrict__ W1,
                             const float* __restrict__ W2,
                             unsigned short* __restrict__ w1p,
                             unsigned short* __restrict__ w2p) {
    int idx = blockIdx.x * blockDim.x + threadIdx.x;
    if (idx < KS1 * 8 * 64 * 8) {
        int j = idx & 7, lane = (idx >> 3) & 63, nt = (idx >> 9) & 7, ks = idx >> 12;
        int k = ks * 32 + (lane >> 4) * 8 + j;
        int n = nt * 16 + (lane & 15);
        w1p[idx] = f2bf(W1[(size_t)k * N_H + n]);
    } else {
        int r = idx - KS1 * 8 * 64 * 8;
        if (r < KS2 * 8 * 64 * 8) {
            int j = r & 7, lane = (r >> 3) & 63, nt = (r >> 9) & 7, ks = r >> 12;
            int k = ks * 32 + (lane >> 4) * 8 + j;
            int n = nt * 16 + (lane & 15);
            w2p[r] = f2bf(W2[(size_t)k * N_H + n]);
        }
    }
}

// Convert node_invariant to bf16 (same row layout) so gather fragments are
// single 16B loads with no per-element conversion in the hot kernel.
__global__ void prep_ninv(const float* __restrict__ ninv,
                          unsigned short* __restrict__ nb, int n4) {
    int i = blockIdx.x * blockDim.x + threadIdx.x;
    if (i < n4) {
        float4 v = ((const float4*)ninv)[i];
        ((ushort4*)nb)[i] = make_ushort4(f2bf(v.x), f2bf(v.y), f2bf(v.z), f2bf(v.w));
    }
}

// 4 independent waves; each owns 32 edges (2 row-tiles). Design goal this
// round: memory-level parallelism. TILES=2 keeps acc at 64 AGPR so the
// 256-reg budget (2 waves/SIMD) leaves ~190 VGPR for in-flight loads:
// all 12 ninv fragments issued up-front, ef fragments prefetched 2 ks
// ahead, weights double-buffered 1 ks ahead.
__global__ __launch_bounds__(256, 2)
void edge_mlp(const unsigned short* __restrict__ ninvb, const float* __restrict__ ef,
              const int* __restrict__ ei,
              const unsigned short* __restrict__ w1p,
              const unsigned short* __restrict__ w2p,
              const float* __restrict__ b1, const float* __restrict__ b2,
              const float* __restrict__ gamma, const float* __restrict__ beta,
              float* __restrict__ out, int E) {
    __shared__ __align__(16) unsigned short hlds[4][TILES][16 * HS];  // 33792 B

    const int tid  = threadIdx.x;
    const int wv   = tid >> 6;
    const int lane = tid & 63;
    const int lr   = lane & 15;
    const int lkg  = lane >> 4;
    const int lk   = lkg * 8;

    const int ebase = (int)blockIdx.x * EPB + wv * EPW;

    int e[TILES], s[TILES], d[TILES];
    #pragma unroll
    for (int t = 0; t < TILES; ++t) {
        int er = ebase + t * 16 + lr;
        e[t] = er < E ? er : E - 1;
        s[t] = ei[e[t]];
        d[t] = ei[(size_t)E + e[t]];
    }

    // ---- issue ALL ninv gather fragments up-front (12 x 16B, independent) ----
    bf16x8 an[TILES][6];
    #pragma unroll
    for (int t = 0; t < TILES; ++t) {
        #pragma unroll
        for (int q = 0; q < 6; ++q) {
            int row = q < 3 ? s[t] : d[t];
            an[t][q] = *(const bf16x8*)(ninvb + (size_t)row * N_INV + (q % 3) * 32 + lk);
        }
    }

    // first weight fragment set (ks=0)
    bf16x8 bfr[2][8];
    #pragma unroll
    for (int nt = 0; nt < 8; ++nt)
        bfr[0][nt] = *(const bf16x8*)(w1p + (nt << 9) + (lane << 3));

    f32x4 efa[TILES][4][2];   // ef A-fragments (f32), rolling prefetch
    f32x4 acc[TILES][8] = {};

    #pragma unroll
    for (int ks = 0; ks < KS1; ++ks) {
        // prefetch next ks weights (double buffer)
        if (ks + 1 < KS1) {
            #pragma unroll
            for (int nt = 0; nt < 8; ++nt)
                bfr[(ks + 1) & 1][nt] =
                    *(const bf16x8*)(w1p + (((ks + 1) * 8 + nt) << 9) + (lane << 3));
        }
        // prefetch ef fragments 2 ks ahead (used at ks 6..9)
        if (ks + 2 >= 6 && ks + 2 < KS1) {
            const int j = ks + 2 - 6;
            #pragma unroll
            for (int t = 0; t < TILES; ++t) {
                const float* ap = ef + (size_t)e[t] * N_H + j * 32 + lk;
                efa[t][j][0] = *(const f32x4*)ap;
                efa[t][j][1] = *(const f32x4*)(ap + 4);
            }
        }
        #pragma unroll
        for (int t = 0; t < TILES; ++t) {
            bf16x8 a;
            if (ks < 6) {
                a = an[t][ks];
            } else {
                const int j = ks - 6;
                union { unsigned short us[8]; bf16x8 b; } ua;
                ua.us[0] = f2bf(efa[t][j][0][0]); ua.us[1] = f2bf(efa[t][j][0][1]);
                ua.us[2] = f2bf(efa[t][j][0][2]); ua.us[3] = f2bf(efa[t][j][0][3]);
                ua.us[4] = f2bf(efa[t][j][1][0]); ua.us[5] = f2bf(efa[t][j][1][1]);
                ua.us[6] = f2bf(efa[t][j][1][2]); ua.us[7] = f2bf(efa[t][j][1][3]);
                a = ua.b;
            }
            #pragma unroll
            for (int nt = 0; nt < 8; ++nt)
                acc[t][nt] = __builtin_amdgcn_mfma_f32_16x16x32_bf16(a, bfr[ks & 1][nt], acc[t][nt], 0, 0, 0);
        }
    }

    // ---- bias + ReLU -> bf16 H tiles (wave-local) ----
    // C/D layout: col = lane&15, row = (lane>>4)*4 + i   [m89]
    const int qr = lkg * 4;
    #pragma unroll
    for (int t = 0; t < TILES; ++t) {
        unsigned short* hw = hlds[wv][t];
        #pragma unroll
        for (int nt = 0; nt < 8; ++nt) {
            float bb = b1[nt * 16 + lr];
            #pragma unroll
            for (int i = 0; i < 4; ++i) {
                float v = acc[t][nt][i] + bb;
                v = v > 0.0f ? v : 0.0f;
                hw[(qr + i) * HS + nt * 16 + lr] = f2bf(v);
            }
        }
    }
    __builtin_amdgcn_wave_barrier();   // same-wave LDS RAW ordering

    // ---- GEMM2 with double-buffered weights ----
    bf16x8 b2fr[2][8];
    #pragma unroll
    for (int nt = 0; nt < 8; ++nt)
        b2fr[0][nt] = *(const bf16x8*)(w2p + (nt << 9) + (lane << 3));

    f32x4 acc2[TILES][8] = {};
    #pragma unroll
    for (int ks = 0; ks < KS2; ++ks) {
        if (ks + 1 < KS2) {
            #pragma unroll
            for (int nt = 0; nt < 8; ++nt)
                b2fr[(ks + 1) & 1][nt] =
                    *(const bf16x8*)(w2p + (((ks + 1) * 8 + nt) << 9) + (lane << 3));
        }
        #pragma unroll
        for (int t = 0; t < TILES; ++t) {
            bf16x8 a = *(const bf16x8*)(&hlds[wv][t][lr * HS + ks * 32 + lk]);
            #pragma unroll
            for (int nt = 0; nt < 8; ++nt)
                acc2[t][nt] = __builtin_amdgcn_mfma_f32_16x16x32_bf16(a, b2fr[ks & 1][nt], acc2[t][nt], 0, 0, 0);
        }
    }

    // ---- per tile: residual prefetch, bias + LayerNorm, store ----
    #pragma unroll
    for (int t = 0; t < TILES; ++t) {
        const int rbase = ebase + t * 16 + qr;

        // issue residual loads first; latency hides under the LN math
        float rres[8][4];
        #pragma unroll
        for (int nt = 0; nt < 8; ++nt) {
            int c = nt * 16 + lr;
            #pragma unroll
            for (int i = 0; i < 4; ++i) {
                int eo = rbase + i;
                int ec = eo < E ? eo : E - 1;
                rres[nt][i] = ef[(size_t)ec * N_H + c];
            }
        }

        float vals[8][4];
        float s1[4] = {0.f, 0.f, 0.f, 0.f};
        float s2[4] = {0.f, 0.f, 0.f, 0.f};
        #pragma unroll
        for (int nt = 0; nt < 8; ++nt) {
            float bb = b2[nt * 16 + lr];
            #pragma unroll
            for (int i = 0; i < 4; ++i) {
                float v = acc2[t][nt][i] + bb;
                vals[nt][i] = v;
                s1[i] += v;
                s2[i] += v * v;
            }
        }
        #pragma unroll
        for (int m = 1; m < 16; m <<= 1) {
            #pragma unroll
            for (int i = 0; i < 4; ++i) {
                s1[i] += __shfl_xor(s1[i], m);
                s2[i] += __shfl_xor(s2[i], m);
            }
        }
        float mu[4], rs[4];
        #pragma unroll
        for (int i = 0; i < 4; ++i) {
            mu[i] = s1[i] * (1.0f / 128.0f);
            float var = s2[i] * (1.0f / 128.0f) - mu[i] * mu[i];
            rs[i] = rsqrtf(var + 1e-5f);
        }

        #pragma unroll
        for (int nt = 0; nt < 8; ++nt) {
            int c = nt * 16 + lr;
            float g  = gamma[c];
            float bt = beta[c];
            #pragma unroll
            for (int i = 0; i < 4; ++i) {
                int eo = rbase + i;
                if (eo < E)
                    out[(size_t)eo * N_H + c] = (vals[nt][i] - mu[i]) * rs[i] * g + bt + rres[nt][i];
            }
        }
    }
}

extern "C" void kernel_launch(void* const* d_in, const int* in_sizes, int n_in,
                              void* d_out, int out_size, void* d_ws, size_t ws_size,
                              hipStream_t stream) {
    const float* ninv = (const float*)d_in[0];
    const float* ef   = (const float*)d_in[1];
    const int*   ei   = (const int*)d_in[2];
    const float* W1   = (const float*)d_in[3];
    const float* b1   = (const float*)d_in[4];
    const float* W2   = (const float*)d_in[5];
    const float* b2   = (const float*)d_in[6];
    const float* g    = (const float*)d_in[7];
    const float* bt   = (const float*)d_in[8];
    float* out = (float*)d_out;

    const int E = in_sizes[1] / N_H;
    const int NNODE = in_sizes[0] / N_INV;

    unsigned short* w1p = (unsigned short*)d_ws;             // 40960 bf16
    unsigned short* w2p = w1p + KS1 * 8 * 64 * 8;            // 16384 bf16
    unsigned short* nb  = w2p + KS2 * 8 * 64 * 8;            // NNODE*96 bf16 (~9.6 MB)

    int prep_total = (KS1 + KS2) * 8 * 64 * 8;
    prep_weights<<<(prep_total + 255) / 256, 256, 0, stream>>>(W1, W2, w1p, w2p);

    int n4 = NNODE * N_INV / 4;
    prep_ninv<<<(n4 + 255) / 256, 256, 0, stream>>>(ninv, nb, n4);

    int nblk = (E + EPB - 1) / EPB;
    edge_mlp<<<nblk, 256, 0, stream>>>(nb, ef, ei, w1p, w2p, b1, b2, g, bt, out, E);
}

// Round 7
// 347.953 us; speedup vs baseline: 3.2788x; 1.0726x over previous
//
#include <hip/hip_runtime.h>
#include <stdint.h>

#define N_H   128
#define N_INV 96
#define N_IN  320
#define HS    132    // bf16 H-tile stride (128+4)
#define EPS   134    // f32 epilogue stride: write banks exactly 2-way (free)
#define TILES 2
#define EPW   (TILES * 16)   // 32 edges per wave
#define EPB   (EPW * 4)      // 128 edges per block

#define KS1   (N_IN / 32)    // 10
#define KS2   (N_H / 32)     // 4

typedef __bf16 bf16x8 __attribute__((ext_vector_type(8)));
typedef float  f32x4  __attribute__((ext_vector_type(4)));

__device__ __forceinline__ unsigned short f2bf(float f) {
    union { float f; unsigned u; } v; v.f = f;
    unsigned u = v.u;
    u += 0x7FFFu + ((u >> 16) & 1u);   // round-to-nearest-even
    return (unsigned short)(u >> 16);
}

// Pack weights in MFMA-fragment order: one contiguous 1KB burst per fragment.
//   w1p[ks][nt][lane][j] = W1[k = ks*32 + (lane>>4)*8 + j][n = nt*16 + (lane&15)]
__global__ void prep_weights(const float* __restrict__ W1,
                             const float* __restrict__ W2,
                             unsigned short* __restrict__ w1p,
                             unsigned short* __restrict__ w2p) {
    int idx = blockIdx.x * blockDim.x + threadIdx.x;
    if (idx < KS1 * 8 * 64 * 8) {
        int j = idx & 7, lane = (idx >> 3) & 63, nt = (idx >> 9) & 7, ks = idx >> 12;
        int k = ks * 32 + (lane >> 4) * 8 + j;
        int n = nt * 16 + (lane & 15);
        w1p[idx] = f2bf(W1[(size_t)k * N_H + n]);
    } else {
        int r = idx - KS1 * 8 * 64 * 8;
        if (r < KS2 * 8 * 64 * 8) {
            int j = r & 7, lane = (r >> 3) & 63, nt = (r >> 9) & 7, ks = r >> 12;
            int k = ks * 32 + (lane >> 4) * 8 + j;
            int n = nt * 16 + (lane & 15);
            w2p[r] = f2bf(W2[(size_t)k * N_H + n]);
        }
    }
}

// Convert node_invariant to bf16 so gather fragments are single 16B loads.
__global__ void prep_ninv(const float* __restrict__ ninv,
                          unsigned short* __restrict__ nb, int n4) {
    int i = blockIdx.x * blockDim.x + threadIdx.x;
    if (i < n4) {
        float4 v = ((const float4*)ninv)[i];
        ((ushort4*)nb)[i] = make_ushort4(f2bf(v.x), f2bf(v.y), f2bf(v.z), f2bf(v.w));
    }
}

// 4 independent waves; each owns 32 edges (2 row-tiles). Registers: acc 64
// AGPR + ~90 VGPR fits 3 waves/SIMD (512/3=170). Epilogue routes LN output
// through a per-wave LDS f32 buffer so residual-load + store are coalesced
// float4 bursts instead of per-fragment scalars.
__global__ __launch_bounds__(256, 3)
void edge_mlp(const unsigned short* __restrict__ ninvb, const float* __restrict__ ef,
              const int* __restrict__ ei,
              const unsigned short* __restrict__ w1p,
              const unsigned short* __restrict__ w2p,
              const float* __restrict__ b1, const float* __restrict__ b2,
              const float* __restrict__ gamma, const float* __restrict__ beta,
              float* __restrict__ out, int E) {
    // per-wave 8704B region: bf16 H tiles (2*16*132*2 = 8448B) before GEMM2,
    // f32 epilogue buffer (16*134*4 = 8576B) after. 4 waves -> 34816B/block.
    __shared__ __align__(16) float smem[4][2176];

    const int tid  = threadIdx.x;
    const int wv   = tid >> 6;
    const int lane = tid & 63;
    const int lr   = lane & 15;
    const int lkg  = lane >> 4;
    const int lk   = lkg * 8;

    const int ebase = (int)blockIdx.x * EPB + wv * EPW;

    int e[TILES], s[TILES], d[TILES];
    #pragma unroll
    for (int t = 0; t < TILES; ++t) {
        int er = ebase + t * 16 + lr;
        e[t] = er < E ? er : E - 1;
        s[t] = ei[e[t]];
        d[t] = ei[(size_t)E + e[t]];
    }

    // ---- issue ALL ninv gather fragments up-front (12 x 16B, independent) ----
    bf16x8 an[TILES][6];
    #pragma unroll
    for (int t = 0; t < TILES; ++t) {
        #pragma unroll
        for (int q = 0; q < 6; ++q) {
            int row = q < 3 ? s[t] : d[t];
            an[t][q] = *(const bf16x8*)(ninvb + (size_t)row * N_INV + (q % 3) * 32 + lk);
        }
    }

    // first weight fragment set (ks=0)
    bf16x8 bfr[2][8];
    #pragma unroll
    for (int nt = 0; nt < 8; ++nt)
        bfr[0][nt] = *(const bf16x8*)(w1p + (nt << 9) + (lane << 3));

    f32x4 efa[TILES][4][2];   // ef A-fragments (f32), rolling prefetch
    f32x4 acc[TILES][8] = {};

    #pragma unroll
    for (int ks = 0; ks < KS1; ++ks) {
        // prefetch next ks weights (double buffer)
        if (ks + 1 < KS1) {
            #pragma unroll
            for (int nt = 0; nt < 8; ++nt)
                bfr[(ks + 1) & 1][nt] =
                    *(const bf16x8*)(w1p + (((ks + 1) * 8 + nt) << 9) + (lane << 3));
        }
        // prefetch ef fragments 2 ks ahead (used at ks 6..9)
        if (ks + 2 >= 6 && ks + 2 < KS1) {
            const int j = ks + 2 - 6;
            #pragma unroll
            for (int t = 0; t < TILES; ++t) {
                const float* ap = ef + (size_t)e[t] * N_H + j * 32 + lk;
                efa[t][j][0] = *(const f32x4*)ap;
                efa[t][j][1] = *(const f32x4*)(ap + 4);
            }
        }
        #pragma unroll
        for (int t = 0; t < TILES; ++t) {
            bf16x8 a;
            if (ks < 6) {
                a = an[t][ks];
            } else {
                const int j = ks - 6;
                union { unsigned short us[8]; bf16x8 b; } ua;
                ua.us[0] = f2bf(efa[t][j][0][0]); ua.us[1] = f2bf(efa[t][j][0][1]);
                ua.us[2] = f2bf(efa[t][j][0][2]); ua.us[3] = f2bf(efa[t][j][0][3]);
                ua.us[4] = f2bf(efa[t][j][1][0]); ua.us[5] = f2bf(efa[t][j][1][1]);
                ua.us[6] = f2bf(efa[t][j][1][2]); ua.us[7] = f2bf(efa[t][j][1][3]);
                a = ua.b;
            }
            #pragma unroll
            for (int nt = 0; nt < 8; ++nt)
                acc[t][nt] = __builtin_amdgcn_mfma_f32_16x16x32_bf16(a, bfr[ks & 1][nt], acc[t][nt], 0, 0, 0);
        }
    }

    // ---- bias + ReLU -> bf16 H tiles (wave-local) ----
    // C/D layout: col = lane&15, row = (lane>>4)*4 + i   [m89]
    const int qr = lkg * 4;
    unsigned short* hw0 = (unsigned short*)smem[wv];
    #pragma unroll
    for (int t = 0; t < TILES; ++t) {
        unsigned short* hw = hw0 + t * 16 * HS;
        #pragma unroll
        for (int nt = 0; nt < 8; ++nt) {
            float bb = b1[nt * 16 + lr];
            #pragma unroll
            for (int i = 0; i < 4; ++i) {
                float v = acc[t][nt][i] + bb;
                v = v > 0.0f ? v : 0.0f;
                hw[(qr + i) * HS + nt * 16 + lr] = f2bf(v);
            }
        }
    }
    __builtin_amdgcn_wave_barrier();   // same-wave LDS RAW ordering

    // ---- GEMM2 with double-buffered weights ----
    bf16x8 b2fr[2][8];
    #pragma unroll
    for (int nt = 0; nt < 8; ++nt)
        b2fr[0][nt] = *(const bf16x8*)(w2p + (nt << 9) + (lane << 3));

    f32x4 acc2[TILES][8] = {};
    #pragma unroll
    for (int ks = 0; ks < KS2; ++ks) {
        if (ks + 1 < KS2) {
            #pragma unroll
            for (int nt = 0; nt < 8; ++nt)
                b2fr[(ks + 1) & 1][nt] =
                    *(const bf16x8*)(w2p + (((ks + 1) * 8 + nt) << 9) + (lane << 3));
        }
        #pragma unroll
        for (int t = 0; t < TILES; ++t) {
            bf16x8 a = *(const bf16x8*)(hw0 + t * 16 * HS + lr * HS + ks * 32 + lk);
            #pragma unroll
            for (int nt = 0; nt < 8; ++nt)
                acc2[t][nt] = __builtin_amdgcn_mfma_f32_16x16x32_bf16(a, b2fr[ks & 1][nt], acc2[t][nt], 0, 0, 0);
        }
    }
    __builtin_amdgcn_wave_barrier();   // GEMM2 LDS reads done before epilogue overwrites

    // ---- per tile: bias + LayerNorm -> LDS f32 -> coalesced residual+store ----
    float* ep = smem[wv];
    #pragma unroll
    for (int t = 0; t < TILES; ++t) {
        float vals[8][4];
        float s1[4] = {0.f, 0.f, 0.f, 0.f};
        float s2[4] = {0.f, 0.f, 0.f, 0.f};
        #pragma unroll
        for (int nt = 0; nt < 8; ++nt) {
            float bb = b2[nt * 16 + lr];
            #pragma unroll
            for (int i = 0; i < 4; ++i) {
                float v = acc2[t][nt][i] + bb;
                vals[nt][i] = v;
                s1[i] += v;
                s2[i] += v * v;
            }
        }
        #pragma unroll
        for (int m = 1; m < 16; m <<= 1) {
            #pragma unroll
            for (int i = 0; i < 4; ++i) {
                s1[i] += __shfl_xor(s1[i], m);
                s2[i] += __shfl_xor(s2[i], m);
            }
        }
        float mu[4], rs[4];
        #pragma unroll
        for (int i = 0; i < 4; ++i) {
            mu[i] = s1[i] * (1.0f / 128.0f);
            float var = s2[i] * (1.0f / 128.0f) - mu[i] * mu[i];
            rs[i] = rsqrtf(var + 1e-5f);
        }

        // scatter normalized values to LDS in fragment layout (writes 2-way = free)
        #pragma unroll
        for (int nt = 0; nt < 8; ++nt) {
            int c = nt * 16 + lr;
            float g  = gamma[c];
            float bt = beta[c];
            #pragma unroll
            for (int i = 0; i < 4; ++i)
                ep[(qr + i) * EPS + c] = (vals[nt][i] - mu[i]) * rs[i] * g + bt;
        }
        __builtin_amdgcn_wave_barrier();

        // coalesced: 8 iters x (float4 LDS read + float4 ef read + float4 store)
        #pragma unroll
        for (int it = 0; it < 8; ++it) {
            int cid  = it * 64 + lane;
            int row  = cid >> 5;
            int c4   = (cid & 31) << 2;
            int erow = ebase + t * 16 + row;
            int ec   = erow < E ? erow : E - 1;
            f32x4 rv = *(const f32x4*)(ef + (size_t)ec * N_H + c4);
            f32x4 nv = *(const f32x4*)(ep + row * EPS + c4);
            f32x4 o  = nv + rv;
            if (erow < E)
                *(f32x4*)(out + (size_t)erow * N_H + c4) = o;
        }
        __builtin_amdgcn_wave_barrier();   // drain reads before next tile's writes
    }
}

extern "C" void kernel_launch(void* const* d_in, const int* in_sizes, int n_in,
                              void* d_out, int out_size, void* d_ws, size_t ws_size,
                              hipStream_t stream) {
    const float* ninv = (const float*)d_in[0];
    const float* ef   = (const float*)d_in[1];
    const int*   ei   = (const int*)d_in[2];
    const float* W1   = (const float*)d_in[3];
    const float* b1   = (const float*)d_in[4];
    const float* W2   = (const float*)d_in[5];
    const float* b2   = (const float*)d_in[6];
    const float* g    = (const float*)d_in[7];
    const float* bt   = (const float*)d_in[8];
    float* out = (float*)d_out;

    const int E = in_sizes[1] / N_H;
    const int NNODE = in_sizes[0] / N_INV;

    unsigned short* w1p = (unsigned short*)d_ws;             // 40960 bf16
    unsigned short* w2p = w1p + KS1 * 8 * 64 * 8;            // 16384 bf16
    unsigned short* nb  = w2p + KS2 * 8 * 64 * 8;            // NNODE*96 bf16 (~9.6 MB)

    int prep_total = (KS1 + KS2) * 8 * 64 * 8;
    prep_weights<<<(prep_total + 255) / 256, 256, 0, stream>>>(W1, W2, w1p, w2p);

    int n4 = NNODE * N_INV / 4;
    prep_ninv<<<(n4 + 255) / 256, 256, 0, stream>>>(ninv, nb, n4);

    int nblk = (E + EPB - 1) / EPB;
    edge_mlp<<<nblk, 256, 0, stream>>>(nb, ef, ei, w1p, w2p, b1, b2, g, bt, out, E);
}

// Round 8
// 329.843 us; speedup vs baseline: 3.4588x; 1.0549x over previous
//
#include <hip/hip_runtime.h>
#include <stdint.h>

#define N_H    128
#define N_INV  96
#define N_IN   320
#define HS     132      // bf16 H-tile stride (128+4), measured 0 conflicts
#define EPSF   134      // f32 epilogue stride (2-way bank alias = free)
#define TILES  2
#define NWAVE  8
#define EPW    (TILES * 16)     // 32 edges per wave
#define EPB    (EPW * NWAVE)    // 256 edges per block
#define KS1    10
#define KS2    4
#define W1_BYTES 81920          // 10*8*64*16
#define W2_BYTES 32768          // 4*8*64*16
#define W_BYTES  (W1_BYTES + W2_BYTES)       // 114688
#define WBUF     4352           // per-wave buffer: max(H 4224, epi-half 4288) rounded
#define SMEM_BYTES (W_BYTES + NWAVE * WBUF)  // 149504

typedef __bf16 bf16x8 __attribute__((ext_vector_type(8)));
typedef float  f32x4  __attribute__((ext_vector_type(4)));

__device__ __forceinline__ unsigned short f2bf(float f) {
    union { float f; unsigned u; } v; v.f = f;
    unsigned u = v.u;
    u += 0x7FFFu + ((u >> 16) & 1u);   // RNE
    return (unsigned short)(u >> 16);
}

// Pack weights in MFMA-fragment order, contiguous w1 then w2 (one linear
// 112KB region for block staging):
//   wpk[(ks*8+nt)*512 + lane*8 + j] = W[k=ks*32+(lane>>4)*8+j][n=nt*16+(lane&15)]
__global__ void prep_weights(const float* __restrict__ W1,
                             const float* __restrict__ W2,
                             unsigned short* __restrict__ w1p,
                             unsigned short* __restrict__ w2p) {
    int idx = blockIdx.x * blockDim.x + threadIdx.x;
    if (idx < KS1 * 8 * 64 * 8) {
        int j = idx & 7, lane = (idx >> 3) & 63, nt = (idx >> 9) & 7, ks = idx >> 12;
        int k = ks * 32 + (lane >> 4) * 8 + j;
        int n = nt * 16 + (lane & 15);
        w1p[idx] = f2bf(W1[(size_t)k * N_H + n]);
    } else {
        int r = idx - KS1 * 8 * 64 * 8;
        if (r < KS2 * 8 * 64 * 8) {
            int j = r & 7, lane = (r >> 3) & 63, nt = (r >> 9) & 7, ks = r >> 12;
            int k = ks * 32 + (lane >> 4) * 8 + j;
            int n = nt * 16 + (lane & 15);
            w2p[r] = f2bf(W2[(size_t)k * N_H + n]);
        }
    }
}

// node_invariant -> bf16 so each gather fragment is a single 16B load.
__global__ void prep_ninv(const float* __restrict__ ninv,
                          unsigned short* __restrict__ nb, int n4) {
    int i = blockIdx.x * blockDim.x + threadIdx.x;
    if (i < n4) {
        float4 v = ((const float4*)ninv)[i];
        ((ushort4*)nb)[i] = make_ushort4(f2bf(v.x), f2bf(v.y), f2bf(v.z), f2bf(v.w));
    }
}

// 8 waves/block. Weights staged once per block into LDS via global_load_lds
// (vmcnt queue freed for the true HBM streams); GEMM inner loops are pure
// LDS/lgkmcnt. Each wave owns 32 edges (2 row-tiles) end-to-end.
__global__ __launch_bounds__(512, 2)
void edge_mlp(const unsigned short* __restrict__ ninvb, const float* __restrict__ ef,
              const int* __restrict__ ei,
              const unsigned short* __restrict__ wpk,
              const float* __restrict__ b1, const float* __restrict__ b2,
              const float* __restrict__ gamma, const float* __restrict__ beta,
              float* __restrict__ out, int E) {
    extern __shared__ __align__(16) char smem[];

    const int tid  = threadIdx.x;
    const int wv   = tid >> 6;
    const int lane = tid & 63;
    const int lr   = lane & 15;
    const int lkg  = lane >> 4;
    const int lk   = lkg * 8;
    const int qr   = lkg * 4;

    const int ebase = (int)blockIdx.x * EPB + wv * EPW;

    // ---- (1) ei loads first: oldest in vmcnt queue, counted waits stay cheap ----
    int e[TILES], s[TILES], d[TILES];
    #pragma unroll
    for (int t = 0; t < TILES; ++t) {
        int er = ebase + t * 16 + lr;
        e[t] = er < E ? er : E - 1;
    }
    #pragma unroll
    for (int t = 0; t < TILES; ++t) { s[t] = ei[e[t]]; d[t] = ei[(size_t)E + e[t]]; }

    // ---- (2) stage 112KB of packed weights to LDS (14 x 1KB chunks per wave) ----
    {
        const char* gsrc = (const char*)wpk;
        #pragma unroll
        for (int i = 0; i < 14; ++i) {
            int c = wv * 14 + i;
            __builtin_amdgcn_global_load_lds(
                (const __attribute__((address_space(1))) void*)(gsrc + c * 1024 + lane * 16),
                (__attribute__((address_space(3))) void*)(smem + c * 1024),
                16, 0, 0);
        }
    }

    // ---- (3) node gathers issued now; they complete under the staging drain ----
    bf16x8 an[TILES][6];
    #pragma unroll
    for (int t = 0; t < TILES; ++t) {
        #pragma unroll
        for (int q = 0; q < 6; ++q) {
            int row = q < 3 ? s[t] : d[t];
            an[t][q] = *(const bf16x8*)(ninvb + (size_t)row * N_INV + (q % 3) * 32 + lk);
        }
    }

    __syncthreads();   // weights visible to all waves

    // ---- GEMM1: A from regs, B from LDS (no vmcnt in loop except efa stream) ----
    f32x4 efa[TILES][4][2];
    f32x4 acc[TILES][8] = {};
    #pragma unroll
    for (int ks = 0; ks < KS1; ++ks) {
        if (ks >= 1 && ks <= 4) {          // prefetch ef fragments, used at ks>=6
            const int j = ks - 1;
            #pragma unroll
            for (int t = 0; t < TILES; ++t) {
                const float* ap = ef + (size_t)e[t] * N_H + j * 32 + lk;
                efa[t][j][0] = *(const f32x4*)ap;
                efa[t][j][1] = *(const f32x4*)(ap + 4);
            }
        }
        bf16x8 bfr[8];
        #pragma unroll
        for (int nt = 0; nt < 8; ++nt)
            bfr[nt] = *(const bf16x8*)(smem + ((ks * 8 + nt) << 10) + (lane << 4));
        #pragma unroll
        for (int t = 0; t < TILES; ++t) {
            bf16x8 a;
            if (ks < 6) {
                a = an[t][ks];
            } else {
                const int j = ks - 6;
                union { unsigned short us[8]; bf16x8 b; } ua;
                ua.us[0] = f2bf(efa[t][j][0][0]); ua.us[1] = f2bf(efa[t][j][0][1]);
                ua.us[2] = f2bf(efa[t][j][0][2]); ua.us[3] = f2bf(efa[t][j][0][3]);
                ua.us[4] = f2bf(efa[t][j][1][0]); ua.us[5] = f2bf(efa[t][j][1][1]);
                ua.us[6] = f2bf(efa[t][j][1][2]); ua.us[7] = f2bf(efa[t][j][1][3]);
                a = ua.b;
            }
            #pragma unroll
            for (int nt = 0; nt < 8; ++nt)
                acc[t][nt] = __builtin_amdgcn_mfma_f32_16x16x32_bf16(a, bfr[nt], acc[t][nt], 0, 0, 0);
        }
    }

    char* buf = smem + W_BYTES + wv * WBUF;           // per-wave scratch
    unsigned short* hb = (unsigned short*)buf;
    float* ep = (float*)buf;

    #pragma unroll
    for (int t = 0; t < TILES; ++t) {
        // ---- bias + ReLU -> bf16 H tile (C/D layout: col=lane&15, row=qr+i) ----
        #pragma unroll
        for (int nt = 0; nt < 8; ++nt) {
            float bb = b1[nt * 16 + lr];
            #pragma unroll
            for (int i = 0; i < 4; ++i) {
                float v = acc[t][nt][i] + bb;
                v = v > 0.0f ? v : 0.0f;
                hb[(qr + i) * HS + nt * 16 + lr] = f2bf(v);
            }
        }
        __builtin_amdgcn_wave_barrier();

        // ---- issue residual loads now; GEMM2 (all-LDS) covers their latency ----
        f32x4 res[2][4];
        #pragma unroll
        for (int h = 0; h < 2; ++h) {
            #pragma unroll
            for (int it = 0; it < 4; ++it) {
                int cid = it * 64 + lane;
                int row = cid >> 5, c4 = (cid & 31) << 2;
                int erow = ebase + t * 16 + 8 * h + row;
                int ec = erow < E ? erow : E - 1;
                res[h][it] = *(const f32x4*)(ef + (size_t)ec * N_H + c4);
            }
        }

        // ---- GEMM2: both operands from LDS ----
        f32x4 acc2[8] = {};
        #pragma unroll
        for (int ks = 0; ks < KS2; ++ks) {
            bf16x8 a = *(const bf16x8*)((const char*)hb + lr * (HS * 2) + ks * 64 + lkg * 16);
            #pragma unroll
            for (int nt = 0; nt < 8; ++nt) {
                bf16x8 w = *(const bf16x8*)(smem + W1_BYTES + ((ks * 8 + nt) << 10) + (lane << 4));
                acc2[nt] = __builtin_amdgcn_mfma_f32_16x16x32_bf16(a, w, acc2[nt], 0, 0, 0);
            }
        }

        // ---- bias + LayerNorm ----
        float vals[8][4];
        float s1[4] = {0.f, 0.f, 0.f, 0.f};
        float s2[4] = {0.f, 0.f, 0.f, 0.f};
        #pragma unroll
        for (int nt = 0; nt < 8; ++nt) {
            float bb = b2[nt * 16 + lr];
            #pragma unroll
            for (int i = 0; i < 4; ++i) {
                float v = acc2[nt][i] + bb;
                vals[nt][i] = v;
                s1[i] += v;
                s2[i] += v * v;
            }
        }
        #pragma unroll
        for (int m = 1; m < 16; m <<= 1) {
            #pragma unroll
            for (int i = 0; i < 4; ++i) {
                s1[i] += __shfl_xor(s1[i], m);
                s2[i] += __shfl_xor(s2[i], m);
            }
        }
        float mu[4], rs[4];
        #pragma unroll
        for (int i = 0; i < 4; ++i) {
            mu[i] = s1[i] * (1.0f / 128.0f);
            float var = s2[i] * (1.0f / 128.0f) - mu[i] * mu[i];
            rs[i] = rsqrtf(var + 1e-5f);
        }

        // ---- epilogue in two 8-row halves through the f32 LDS buffer ----
        #pragma unroll
        for (int h = 0; h < 2; ++h) {
            if ((lkg >> 1) == h) {        // this lane's rows are in half h
                #pragma unroll
                for (int nt = 0; nt < 8; ++nt) {
                    int c = nt * 16 + lr;
                    float g  = gamma[c];
                    float bt = beta[c];
                    #pragma unroll
                    for (int i = 0; i < 4; ++i)
                        ep[(qr - 8 * h + i) * EPSF + c] = (vals[nt][i] - mu[i]) * rs[i] * g + bt;
                }
            }
            __builtin_amdgcn_wave_barrier();
            #pragma unroll
            for (int it = 0; it < 4; ++it) {
                int cid = it * 64 + lane;
                int row = cid >> 5, c4 = (cid & 31) << 2;
                int erow = ebase + t * 16 + 8 * h + row;
                if (erow < E) {
                    f32x4 nv = *(const f32x4*)(ep + row * EPSF + c4);
                    *(f32x4*)(out + (size_t)erow * N_H + c4) = nv + res[h][it];
                }
            }
            __builtin_amdgcn_wave_barrier();
        }
    }
}

extern "C" void kernel_launch(void* const* d_in, const int* in_sizes, int n_in,
                              void* d_out, int out_size, void* d_ws, size_t ws_size,
                              hipStream_t stream) {
    const float* ninv = (const float*)d_in[0];
    const float* ef   = (const float*)d_in[1];
    const int*   ei   = (const int*)d_in[2];
    const float* W1   = (const float*)d_in[3];
    const float* b1   = (const float*)d_in[4];
    const float* W2   = (const float*)d_in[5];
    const float* b2   = (const float*)d_in[6];
    const float* g    = (const float*)d_in[7];
    const float* bt   = (const float*)d_in[8];
    float* out = (float*)d_out;

    const int E = in_sizes[1] / N_H;
    const int NNODE = in_sizes[0] / N_INV;

    unsigned short* w1p = (unsigned short*)d_ws;             // 40960 bf16
    unsigned short* w2p = w1p + KS1 * 8 * 64 * 8;            // 16384 bf16 (contiguous!)
    unsigned short* nb  = w2p + KS2 * 8 * 64 * 8;            // NNODE*96 bf16

    hipFuncSetAttribute((const void*)edge_mlp,
                        hipFuncAttributeMaxDynamicSharedMemorySize, SMEM_BYTES);

    int prep_total = (KS1 + KS2) * 8 * 64 * 8;
    prep_weights<<<(prep_total + 255) / 256, 256, 0, stream>>>(W1, W2, w1p, w2p);

    int n4 = NNODE * N_INV / 4;
    prep_ninv<<<(n4 + 255) / 256, 256, 0, stream>>>(ninv, nb, n4);

    int nblk = (E + EPB - 1) / EPB;
    edge_mlp<<<nblk, 512, SMEM_BYTES, stream>>>(nb, ef, ei, w1p, b1, b2, g, bt, out, E);
}